// Round 1
// baseline (1533.186 us; speedup 1.0000x reference)
//
#include <hip/hip_runtime.h>

#define T_STEPS 1024
#define B_TOT   512
#define EMB     64
#define HID     64
#define GATES   256   // 4*HID
#define R       2     // batch rows per block

__device__ __forceinline__ float fast_rcp(float x)  { return __builtin_amdgcn_rcpf(x); }
__device__ __forceinline__ float fast_exp2(float x) { return __builtin_amdgcn_exp2f(x); }

__device__ __forceinline__ float sigmoid_f(float x) {
    // 1 / (1 + exp(-x)) = 1 / (1 + 2^(-x*log2e))
    return fast_rcp(1.0f + fast_exp2(-1.4426950408889634f * x));
}
__device__ __forceinline__ float tanh_f(float x) {
    // tanh(x) = 1 - 2/(exp(2x)+1);  exp(2x) = 2^(x*2*log2e)
    float e = fast_exp2(2.8853900817779268f * x);
    return 1.0f - 2.0f * fast_rcp(e + 1.0f);
}

__global__ __launch_bounds__(256, 2)
void lstm_bidir_kernel(const int* __restrict__ tokens,
                       const float* __restrict__ emb,
                       const float* __restrict__ Wx_f, const float* __restrict__ Wh_f,
                       const float* __restrict__ b_f,
                       const float* __restrict__ Wx_b, const float* __restrict__ Wh_b,
                       const float* __restrict__ b_b,
                       float* __restrict__ out)
{
    const int bx   = blockIdx.x;       // 0..511
    const int dir  = bx >> 8;          // 0 = fwd, 1 = bwd
    const int row0 = (bx & 255) * R;   // global batch row base
    const int j    = threadIdx.x;      // gate column 0..255

    const float* __restrict__ Wx = dir ? Wx_b : Wx_f;
    const float* __restrict__ Wh = dir ? Wh_b : Wh_f;
    const float* __restrict__ bv = dir ? b_b  : b_f;

    // Register-resident weight columns (128 VGPRs), reused for all 1024 steps.
    float wx[EMB];
    float wh[HID];
#pragma unroll
    for (int k = 0; k < EMB; ++k) wx[k] = Wx[k * GATES + j];   // coalesced: lane j -> col j
#pragma unroll
    for (int k = 0; k < HID; ++k) wh[k] = Wh[k * GATES + j];
    const float bias = bv[j];

    __shared__ float4 x4[2][R][EMB / 4];   // double-buffered embedded inputs
    __shared__ float4 h4[R][HID / 4];      // hidden state
    __shared__ float  z_lds[R][GATES];     // pre-activation gates
    __shared__ int    tok_lds[2][R];       // token (for mask) per buffered step

    const bool is_gather = (j >= 128 && j < 128 + R * (EMB / 4));   // 32 threads
    const int  gr = (j - 128) >> 4;                                  // gather row
    const int  gq = (j - 128) & 15;                                  // float4 index

    // init h = 0
    if (j < R * (HID / 4)) {
        int r = j / (HID / 4), q = j % (HID / 4);
        h4[r][q] = make_float4(0.f, 0.f, 0.f, 0.f);
    }

    // prologue: load x(step 0) into buf 0; preload token(step 1)
    int tok_cur = 0;   // token value for step t+1 (gather threads only)
    if (is_gather) {
        int s0 = dir ? (T_STEPS - 1) : 0;
        int tok0 = tokens[(row0 + gr) * T_STEPS + s0];
        x4[0][gr][gq] = ((const float4*)emb)[tok0 * (EMB / 4) + gq];
        if (gq == 0) tok_lds[0][gr] = tok0;
        int s1 = dir ? (T_STEPS - 2) : 1;
        tok_cur = tokens[(row0 + gr) * T_STEPS + s1];
    }
    float c_state = 0.0f;  // cell state, meaningful for threads j < R*HID
    __syncthreads();

#pragma unroll 1
    for (int t = 0; t < T_STEPS; ++t) {
        const int buf = t & 1;

        // Issue next-step global loads EARLY so their latency hides under the FMA block.
        float4 xfetch;
        int tok_fut = 0;
        if (is_gather) {
            xfetch = ((const float4*)emb)[tok_cur * (EMB / 4) + gq];     // x for step t+1
            int s2 = (t + 2 < T_STEPS) ? (t + 2) : (T_STEPS - 1);        // clamped
            int sp = dir ? (T_STEPS - 1 - s2) : s2;
            tok_fut = tokens[(row0 + gr) * T_STEPS + sp];                // token for step t+2
        }

        // ---- phase A: z[r][j] = b[j] + x.wx + h.wh (4 independent accumulators) ----
        float zr[R];
#pragma unroll
        for (int r = 0; r < R; ++r) {
            float a0 = bias, a1 = 0.f, a2 = 0.f, a3 = 0.f;
#pragma unroll
            for (int q = 0; q < HID / 4; ++q) {
                float4 hv = h4[r][q];                 // LDS broadcast (all lanes same addr)
                a0 = fmaf(hv.x, wh[4 * q + 0], a0);
                a1 = fmaf(hv.y, wh[4 * q + 1], a1);
                a2 = fmaf(hv.z, wh[4 * q + 2], a2);
                a3 = fmaf(hv.w, wh[4 * q + 3], a3);
            }
#pragma unroll
            for (int q = 0; q < EMB / 4; ++q) {
                float4 xv = x4[buf][r][q];            // LDS broadcast
                a0 = fmaf(xv.x, wx[4 * q + 0], a0);
                a1 = fmaf(xv.y, wx[4 * q + 1], a1);
                a2 = fmaf(xv.z, wx[4 * q + 2], a2);
                a3 = fmaf(xv.w, wx[4 * q + 3], a3);
            }
            zr[r] = (a0 + a1) + (a2 + a3);
        }
#pragma unroll
        for (int r = 0; r < R; ++r) z_lds[r][j] = zr[r];   // conflict-free (stride-1)
        __syncthreads();

        // ---- phase B: gate nonlinearities + state update (threads 0..127),
        //               x prefetch LDS write (gather threads) ----
        if (j < R * HID) {
            const int r = j >> 6, u = j & 63;
            float zi = z_lds[r][u];
            float zf = z_lds[r][HID + u];
            float zg = z_lds[r][2 * HID + u];
            float zo = z_lds[r][3 * HID + u];
            float ig = sigmoid_f(zi);
            float fg = sigmoid_f(zf);
            float og = sigmoid_f(zo);
            float gg = tanh_f(zg);
            float c_new = fmaf(fg, c_state, ig * gg);
            float h_new = og * tanh_f(c_new);
            if (tok_lds[buf][r] != 0) {     // Keras mask_zero: padded step carries state
                c_state = c_new;
                ((float*)h4)[r * HID + u] = h_new;
            }
        } else if (is_gather && (t + 1 < T_STEPS)) {
            x4[buf ^ 1][gr][gq] = xfetch;
            if (gq == 0) tok_lds[buf ^ 1][gr] = tok_cur;
            tok_cur = tok_fut;
        }
        __syncthreads();
    }

    // epilogue: final h -> out[row][dir*64 + u]
    if (j < R * HID) {
        const int r = j >> 6, u = j & 63;
        out[(row0 + r) * (2 * HID) + dir * HID + u] = ((float*)h4)[r * HID + u];
    }
}

extern "C" void kernel_launch(void* const* d_in, const int* in_sizes, int n_in,
                              void* d_out, int out_size, void* d_ws, size_t ws_size,
                              hipStream_t stream) {
    const int*   tokens = (const int*)  d_in[0];
    const float* emb    = (const float*)d_in[1];
    const float* Wx_f   = (const float*)d_in[2];
    const float* Wh_f   = (const float*)d_in[3];
    const float* b_f    = (const float*)d_in[4];
    const float* Wx_b   = (const float*)d_in[5];
    const float* Wh_b   = (const float*)d_in[6];
    const float* b_b    = (const float*)d_in[7];
    float* out = (float*)d_out;

    dim3 grid(2 * (B_TOT / R));   // 512 blocks: [dir | row-chunk]
    dim3 block(GATES);            // 256 threads = 256 gate columns
    hipLaunchKernelGGL(lstm_bidir_kernel, grid, block, 0, stream,
                       tokens, emb, Wx_f, Wh_f, b_f, Wx_b, Wh_b, b_b, out);
}

// Round 2
// 992.981 us; speedup vs baseline: 1.5440x; 1.5440x over previous
//
#include <hip/hip_runtime.h>

#define T_STEPS 1024
#define B_TOT   512
#define VOCAB   1000
#define EMB     64
#define HID     64
#define GATES   256   // 4*HID

__device__ __forceinline__ float fast_rcp(float x)  { return __builtin_amdgcn_rcpf(x); }
__device__ __forceinline__ float fast_exp2(float x) { return __builtin_amdgcn_exp2f(x); }

__device__ __forceinline__ float sigmoid_f(float x) {
    // 1 / (1 + 2^(-x*log2e))
    return fast_rcp(1.0f + fast_exp2(-1.4426950408889634f * x));
}
__device__ __forceinline__ float tanh_f(float x) {
    // 1 - 2/(exp(2x)+1)
    float e = fast_exp2(2.8853900817779268f * x);
    return 1.0f - 2.0f * fast_rcp(e + 1.0f);
}

// ---------------------------------------------------------------------------
// Kernel 1: zx_tab[dir][v][j] = b[dir][j] + sum_k emb[v][k] * Wx[dir][k][j]
// x_t @ Wx depends only on the token id (VOCAB=1000 distinct values), so the
// entire input projection collapses to a 2 MB lookup table.
// ---------------------------------------------------------------------------
__global__ __launch_bounds__(256, 4)
void zx_table_kernel(const float* __restrict__ emb,
                     const float* __restrict__ Wx_f, const float* __restrict__ b_f,
                     const float* __restrict__ Wx_b, const float* __restrict__ b_b,
                     float* __restrict__ zx_tab)
{
    const int bid = blockIdx.x;            // 0..1999
    const int dir = bid / VOCAB;
    const int v   = bid - dir * VOCAB;
    const int j   = threadIdx.x;           // gate column

    const float* __restrict__ Wx = dir ? Wx_b : Wx_f;
    const float* __restrict__ bv = dir ? b_b  : b_f;

    __shared__ float4 x4[EMB / 4];
    if (j < EMB / 4) x4[j] = ((const float4*)emb)[v * (EMB / 4) + j];
    __syncthreads();

    float a0 = bv[j], a1 = 0.f, a2 = 0.f, a3 = 0.f;
#pragma unroll
    for (int q = 0; q < EMB / 4; ++q) {
        float4 xv = x4[q];                              // LDS broadcast
        a0 = fmaf(xv.x, Wx[(4 * q + 0) * GATES + j], a0);  // coalesced col loads
        a1 = fmaf(xv.y, Wx[(4 * q + 1) * GATES + j], a1);
        a2 = fmaf(xv.z, Wx[(4 * q + 2) * GATES + j], a2);
        a3 = fmaf(xv.w, Wx[(4 * q + 3) * GATES + j], a3);
    }
    zx_tab[(dir * VOCAB + v) * GATES + j] = (a0 + a1) + (a2 + a3);
}

// ---------------------------------------------------------------------------
// Kernel 2: the recurrence. One block per (dir, row): 1024 blocks = 4/CU.
// Thread j owns gate column j: 64 Wh weights in VGPRs (fits the 128-VGPR cap
// from launch_bounds(256,4) -> no AGPR round-trips). Per step:
//   z[j] = zx_tab[tok] (prefetched 1 step ahead) + h . wh   (64 FMA)
// Tokens are wave-uniform scalar loads, 2-step prefetch chain; mask is a
// uniform branch (Keras mask_zero: state carried through padded steps).
// ---------------------------------------------------------------------------
__global__ __launch_bounds__(256, 4)
void lstm_rec_kernel(const int* __restrict__ tokens,
                     const float* __restrict__ Wh_f,
                     const float* __restrict__ Wh_b,
                     const float* __restrict__ zx_tab,
                     float* __restrict__ out)
{
    const int bx  = blockIdx.x;        // 0..1023
    const int dir = bx >> 9;           // 0 fwd, 1 bwd
    const int row = bx & 511;
    const int j   = threadIdx.x;       // gate column

    const float* __restrict__ Wh   = dir ? Wh_b : Wh_f;
    const float* __restrict__ zx   = zx_tab + dir * (VOCAB * GATES);
    const int*   __restrict__ trow = tokens + row * T_STEPS;

    // 64 register-resident weights, reused all 1024 steps.
    float wh[HID];
#pragma unroll
    for (int k = 0; k < HID; ++k) wh[k] = Wh[k * GATES + j];

    __shared__ float4 h4[HID / 4];     // hidden state, broadcast-read
    __shared__ float  z_lds[GATES];    // pre-activations

    if (j < HID / 4) h4[j] = make_float4(0.f, 0.f, 0.f, 0.f);
    float c = 0.0f;                    // cell state (threads j < 64)

    // token prefetch chain (wave-uniform -> SGPR scalar loads)
    int tokc = trow[dir ? (T_STEPS - 1) : 0];      // token for step t
    int tokn = trow[dir ? (T_STEPS - 2) : 1];      // token for step t+1
    float zxc = zx[tokc * GATES + j];              // zx for step t
    __syncthreads();

#pragma unroll 1
    for (int t = 0; t < T_STEPS; ++t) {
        // --- prefetches issued first: latency hides under the FMA block ---
        int t2 = (t + 2 < T_STEPS) ? (t + 2) : (T_STEPS - 1);
        int tokf = trow[dir ? (T_STEPS - 1 - t2) : t2];   // token t+2 (uniform)
        float zxn = zx[tokn * GATES + j];                 // zx row for t+1

        // --- phase A: z = zx + h.wh, 4 independent accumulators ---
        float a0 = zxc, a1 = 0.f, a2 = 0.f, a3 = 0.f;
#pragma unroll
        for (int q = 0; q < HID / 4; ++q) {
            float4 hv = h4[q];                 // LDS broadcast (conflict-free)
            a0 = fmaf(hv.x, wh[4 * q + 0], a0);
            a1 = fmaf(hv.y, wh[4 * q + 1], a1);
            a2 = fmaf(hv.z, wh[4 * q + 2], a2);
            a3 = fmaf(hv.w, wh[4 * q + 3], a3);
        }
        z_lds[j] = (a0 + a1) + (a2 + a3);
        __syncthreads();

        // --- phase B: gates + state update (wave 0 only; uniform mask) ---
        if (tokc != 0 && j < HID) {
            float zi = z_lds[j];
            float zf = z_lds[HID + j];
            float zg = z_lds[2 * HID + j];
            float zo = z_lds[3 * HID + j];
            float ig = sigmoid_f(zi);
            float fg = sigmoid_f(zf);
            float og = sigmoid_f(zo);
            float gg = tanh_f(zg);
            c = fmaf(fg, c, ig * gg);
            ((float*)h4)[j] = og * tanh_f(c);
        }
        __syncthreads();

        tokc = tokn; tokn = tokf; zxc = zxn;
    }

    if (j < HID)
        out[row * (2 * HID) + dir * HID + j] = ((float*)h4)[j];
}

extern "C" void kernel_launch(void* const* d_in, const int* in_sizes, int n_in,
                              void* d_out, int out_size, void* d_ws, size_t ws_size,
                              hipStream_t stream) {
    const int*   tokens = (const int*)  d_in[0];
    const float* emb    = (const float*)d_in[1];
    const float* Wx_f   = (const float*)d_in[2];
    const float* Wh_f   = (const float*)d_in[3];
    const float* b_f    = (const float*)d_in[4];
    const float* Wx_b   = (const float*)d_in[5];
    const float* Wh_b   = (const float*)d_in[6];
    const float* b_b    = (const float*)d_in[7];
    float* out = (float*)d_out;

    float* zx_tab = (float*)d_ws;   // needs 2*1000*256*4 = 1.95 MB of d_ws

    hipLaunchKernelGGL(zx_table_kernel, dim3(2 * VOCAB), dim3(GATES), 0, stream,
                       emb, Wx_f, b_f, Wx_b, b_b, zx_tab);
    hipLaunchKernelGGL(lstm_rec_kernel, dim3(2 * (B_TOT)), dim3(GATES), 0, stream,
                       tokens, Wh_f, Wh_b, zx_tab, out);
}

// Round 3
// 672.506 us; speedup vs baseline: 2.2798x; 1.4765x over previous
//
#include <hip/hip_runtime.h>

#define T_STEPS 1024
#define B_TOT   512
#define VOCAB   1000
#define EMB     64
#define HID     64
#define GATES   256   // 4*HID

typedef float v2f __attribute__((ext_vector_type(2)));

__device__ __forceinline__ float fast_rcp(float x)  { return __builtin_amdgcn_rcpf(x); }
__device__ __forceinline__ float fast_exp2(float x) { return __builtin_amdgcn_exp2f(x); }

__device__ __forceinline__ float sigmoid_f(float x) {
    return fast_rcp(1.0f + fast_exp2(-1.4426950408889634f * x));
}
__device__ __forceinline__ float tanh_f(float x) {
    float e = fast_exp2(2.8853900817779268f * x);
    return 1.0f - 2.0f * fast_rcp(e + 1.0f);
}

// packed fp32 FMA: acc.lo += a.lo*b.lo ; acc.hi += a.hi*b.hi  (1 instr, 2 MACs)
__device__ __forceinline__ void pk_fma_acc(v2f& acc, v2f a, v2f b) {
    asm("v_pk_fma_f32 %0, %1, %2, %0" : "+v"(acc) : "v"(a), "v"(b));
}

// ---------------------------------------------------------------------------
// Kernel 1: zx_tab[dir][v][j] = b[dir][j] + sum_k emb[v][k] * Wx[dir][k][j]
// The input projection depends only on token id -> 2 MB lookup table in d_ws.
// ---------------------------------------------------------------------------
__global__ __launch_bounds__(256, 4)
void zx_table_kernel(const float* __restrict__ emb,
                     const float* __restrict__ Wx_f, const float* __restrict__ b_f,
                     const float* __restrict__ Wx_b, const float* __restrict__ b_b,
                     float* __restrict__ zx_tab)
{
    const int bid = blockIdx.x;            // 0..1999
    const int dir = bid / VOCAB;
    const int v   = bid - dir * VOCAB;
    const int j   = threadIdx.x;

    const float* __restrict__ Wx = dir ? Wx_b : Wx_f;
    const float* __restrict__ bv = dir ? b_b  : b_f;

    __shared__ float4 x4[EMB / 4];
    if (j < EMB / 4) x4[j] = ((const float4*)emb)[v * (EMB / 4) + j];
    __syncthreads();

    float a0 = bv[j], a1 = 0.f, a2 = 0.f, a3 = 0.f;
#pragma unroll
    for (int q = 0; q < EMB / 4; ++q) {
        float4 xv = x4[q];
        a0 = fmaf(xv.x, Wx[(4 * q + 0) * GATES + j], a0);
        a1 = fmaf(xv.y, Wx[(4 * q + 1) * GATES + j], a1);
        a2 = fmaf(xv.z, Wx[(4 * q + 2) * GATES + j], a2);
        a3 = fmaf(xv.w, Wx[(4 * q + 3) * GATES + j], a3);
    }
    zx_tab[(dir * VOCAB + v) * GATES + j] = (a0 + a1) + (a2 + a3);
}

// ---------------------------------------------------------------------------
// Kernel 2: recurrence. One block per (dir,row). Thread j owns gate column j
// (wave w = gate w, lane u = hidden unit u -> all gate branches wave-uniform).
// Per step:
//   phase A: z[j] = zx_tab[tok][j] + h . wh[j]   (32 v_pk_fma_f32)
//            act[j] = gate-activation(z[j])      (applied by the owner thread,
//                                                 parallel across all 4 waves)
//   barrier
//   update (wave 0): c = sig(f)*c + sig(i)*tanh(g); h = sig(o)*tanh(c)
//            i-gate act is wave 0's own register; f,g,o from LDS.
//   barrier
// ---------------------------------------------------------------------------
__global__ __launch_bounds__(256, 4)
void lstm_rec_kernel(const int* __restrict__ tokens,
                     const float* __restrict__ Wh_f,
                     const float* __restrict__ Wh_b,
                     const float* __restrict__ zx_tab,
                     float* __restrict__ out)
{
    const int bx  = blockIdx.x;        // 0..1023
    const int dir = bx >> 9;
    const int row = bx & 511;
    const int j   = threadIdx.x;

    const float* __restrict__ Wh   = dir ? Wh_b : Wh_f;
    const float* __restrict__ zx   = zx_tab + dir * (VOCAB * GATES);
    const int*   __restrict__ trow = tokens + row * T_STEPS;

    // 64 weights as 32 packed pairs (64 VGPRs), reused all 1024 steps.
    v2f whp[HID / 2];
#pragma unroll
    for (int m = 0; m < HID / 2; ++m) {
        v2f w; w.x = Wh[(2 * m) * GATES + j]; w.y = Wh[(2 * m + 1) * GATES + j];
        whp[m] = w;
    }

    __shared__ float4 h4[HID / 4];     // hidden state (broadcast-read)
    __shared__ float  act_lds[GATES];  // activated gates

    if (j < HID / 4) h4[j] = make_float4(0.f, 0.f, 0.f, 0.f);
    float c = 0.0f;                    // cell state (wave 0 lanes)

    // wave-uniform token prefetch chain (scalar loads)
    int tokc = trow[dir ? (T_STEPS - 1) : 0];
    int tokn = trow[dir ? (T_STEPS - 2) : 1];
    float zxc = zx[tokc * GATES + j];
    __syncthreads();

#pragma unroll 1
    for (int t = 0; t < T_STEPS; ++t) {
        // prefetches first: latency hides under the pk_fma block
        int t2 = (t + 2 < T_STEPS) ? (t + 2) : (T_STEPS - 1);
        int tokf = trow[dir ? (T_STEPS - 1 - t2) : t2];
        float zxn = zx[tokn * GATES + j];

        // ---- phase A: z = zx + h.wh (packed, 2 independent chains) ----
        v2f acc0; acc0.x = zxc; acc0.y = 0.f;
        v2f acc1; acc1.x = 0.f; acc1.y = 0.f;
#pragma unroll
        for (int q = 0; q < HID / 4; ++q) {
            float4 hv = h4[q];                       // LDS broadcast
            v2f hlo; hlo.x = hv.x; hlo.y = hv.y;
            v2f hhi; hhi.x = hv.z; hhi.y = hv.w;
            pk_fma_acc(acc0, hlo, whp[2 * q]);
            pk_fma_acc(acc1, hhi, whp[2 * q + 1]);
        }
        float z = (acc0.x + acc1.x) + (acc0.y + acc1.y);

        // ---- own-gate activation (wave-uniform branch) ----
        const int gate = j >> 6;                     // == wave id
        float act = (gate == 2) ? tanh_f(z) : sigmoid_f(z);
        if (gate != 0) act_lds[j] = act;             // wave 0 keeps i in reg
        __syncthreads();

        // ---- update: wave 0 only; i is the local register ----
        if (j < HID) {
            float fg = act_lds[HID + j];
            float gg = act_lds[2 * HID + j];
            float og = act_lds[3 * HID + j];
            if (tokc != 0) {                         // Keras mask_zero carry
                c = fmaf(fg, c, act * gg);
                ((float*)h4)[j] = og * tanh_f(c);
            }
        }
        __syncthreads();

        tokc = tokn; tokn = tokf; zxc = zxn;
    }

    if (j < HID)
        out[row * (2 * HID) + dir * HID + j] = ((float*)h4)[j];
}

extern "C" void kernel_launch(void* const* d_in, const int* in_sizes, int n_in,
                              void* d_out, int out_size, void* d_ws, size_t ws_size,
                              hipStream_t stream) {
    const int*   tokens = (const int*)  d_in[0];
    const float* emb    = (const float*)d_in[1];
    const float* Wx_f   = (const float*)d_in[2];
    const float* Wh_f   = (const float*)d_in[3];
    const float* b_f    = (const float*)d_in[4];
    const float* Wx_b   = (const float*)d_in[5];
    const float* Wh_b   = (const float*)d_in[6];
    const float* b_b    = (const float*)d_in[7];
    float* out = (float*)d_out;

    float* zx_tab = (float*)d_ws;   // 2*1000*256*4 = 1.95 MB of d_ws

    hipLaunchKernelGGL(zx_table_kernel, dim3(2 * VOCAB), dim3(GATES), 0, stream,
                       emb, Wx_f, b_f, Wx_b, b_b, zx_tab);
    hipLaunchKernelGGL(lstm_rec_kernel, dim3(2 * B_TOT), dim3(GATES), 0, stream,
                       tokens, Wh_f, Wh_b, zx_tab, out);
}

// Round 5
// 626.245 us; speedup vs baseline: 2.4482x; 1.0739x over previous
//
#include <hip/hip_runtime.h>

#define T_STEPS 1024
#define B_TOT   512
#define VOCAB   1000
#define EMB     64
#define HID     64
#define GATES   256   // 4*HID

typedef float f4 __attribute__((ext_vector_type(4)));
typedef float f2 __attribute__((ext_vector_type(2)));

__device__ __forceinline__ float fast_rcp(float x)  { return __builtin_amdgcn_rcpf(x); }
__device__ __forceinline__ float fast_exp2(float x) { return __builtin_amdgcn_exp2f(x); }

__device__ __forceinline__ float sigmoid_f(float x) {
    return fast_rcp(1.0f + fast_exp2(-1.4426950408889634f * x));
}
__device__ __forceinline__ float tanh_f(float x) {
    float e = fast_exp2(2.8853900817779268f * x);
    return 1.0f - 2.0f * fast_rcp(e + 1.0f);
}

// ---------------------------------------------------------------------------
// Kernel 1: zx table. Layout [dir][vocab][wave][unit][pair]:
//   thread j (0..255): p=j&1, u=(j>>1)&63, w=j>>7, source col=(2w+p)*64+u.
// The recurrent kernel's lane (w,u) then gathers one coalesced float2
// = (z_gate(2w), z_gate(2w+1)) at float2-index tok*128 + w*64 + u.
// ---------------------------------------------------------------------------
__global__ __launch_bounds__(256, 4)
void zx_table_kernel(const float* __restrict__ emb,
                     const float* __restrict__ Wx_f, const float* __restrict__ b_f,
                     const float* __restrict__ Wx_b, const float* __restrict__ b_b,
                     float* __restrict__ zx_tab)
{
    const int bid = blockIdx.x;            // 0..1999
    const int dir = bid / VOCAB;
    const int v   = bid - dir * VOCAB;
    const int j   = threadIdx.x;
    const int p   = j & 1;
    const int u   = (j >> 1) & 63;
    const int w   = j >> 7;
    const int col = (2 * w + p) * HID + u;

    const float* __restrict__ Wx = dir ? Wx_b : Wx_f;
    const float* __restrict__ bv = dir ? b_b  : b_f;

    __shared__ float4 x4[EMB / 4];
    if (j < EMB / 4) x4[j] = ((const float4*)emb)[v * (EMB / 4) + j];
    __syncthreads();

    float a0 = bv[col], a1 = 0.f, a2 = 0.f, a3 = 0.f;
#pragma unroll
    for (int q = 0; q < EMB / 4; ++q) {
        float4 xv = x4[q];
        a0 = fmaf(xv.x, Wx[(4 * q + 0) * GATES + col], a0);
        a1 = fmaf(xv.y, Wx[(4 * q + 1) * GATES + col], a1);
        a2 = fmaf(xv.z, Wx[(4 * q + 2) * GATES + col], a2);
        a3 = fmaf(xv.w, Wx[(4 * q + 3) * GATES + col], a3);
    }
    zx_tab[(dir * VOCAB + v) * GATES + j] = (a0 + a1) + (a2 + a3);
}

// ---------------------------------------------------------------------------
// Kernel 2: recurrence, all fp32. One block (128 thr = 2 waves) per
// (dir,row): 1024 blocks -> 8 waves/CU = 2 waves/SIMD, so a co-resident
// block's FMA stream covers this block's barrier/LDS stalls.
//   wave 0, lane u: gates i,f of unit u (128 register weights, fp32)
//   wave 1, lane u: gates g,o of unit u
// Per step: 128 fmac/lane (8 chains) -> own-gate activations (2 trans/lane,
// all 128 lanes busy) -> wave1 writes float2{g,o} -> barrier -> wave0 does
// lane-parallel c/h update, writes h -> barrier.
// ---------------------------------------------------------------------------
__global__ __launch_bounds__(128, 2)
void lstm_rec_kernel(const int* __restrict__ tokens,
                     const float* __restrict__ Wh_f,
                     const float* __restrict__ Wh_b,
                     const float* __restrict__ zx_tab,
                     float* __restrict__ out)
{
    const int bx  = blockIdx.x;        // 0..1023
    const int dir = bx >> 9;
    const int row = bx & 511;
    const int u   = threadIdx.x & 63;  // hidden unit
    const int w   = threadIdx.x >> 6;  // wave id: 0 -> gates i,f ; 1 -> g,o

    const float* __restrict__ Wh   = dir ? Wh_b : Wh_f;
    const f2*    __restrict__ zx2  = (const f2*)(zx_tab + dir * (VOCAB * GATES));
    const int*   __restrict__ trow = tokens + row * T_STEPS;

    // 128 register-resident fp32 weights: columns (2w)*64+u and (2w+1)*64+u.
    const int colA = (2 * w) * HID + u;
    const int colB = colA + HID;
    float whA[HID], whB[HID];
#pragma unroll
    for (int k = 0; k < HID; ++k) whA[k] = Wh[k * GATES + colA];
#pragma unroll
    for (int k = 0; k < HID; ++k) whB[k] = Wh[k * GATES + colB];

    __shared__ float hbuf[HID];        // h broadcast (fp32)
    __shared__ f2    act2[HID];        // wave1 -> wave0: {g, o}

    if (threadIdx.x < HID) hbuf[threadIdx.x] = 0.0f;
    float c = 0.0f;                    // cell state (wave 0 lanes)
    __syncthreads();

    // wave-uniform token chain + zx prefetch (float2 per lane)
    int tokc = trow[dir ? (T_STEPS - 1) : 0];
    int tokn = trow[dir ? (T_STEPS - 2) : 1];
    f2  zxc  = zx2[tokc * 128 + w * 64 + u];

    const f4* __restrict__ hb4 = (const f4*)hbuf;

#pragma unroll 1
    for (int t = 0; t < T_STEPS; ++t) {
        // prefetches first: latency hides under the fmac block
        int t2   = (t + 2 < T_STEPS) ? (t + 2) : (T_STEPS - 1);
        int tokf = trow[dir ? (T_STEPS - 1 - t2) : t2];
        f2  zxn  = zx2[tokn * 128 + w * 64 + u];

        // ---- two 64-dim dots, 8 independent fmac chains ----
        float aA0 = zxc.x, aA1 = 0.f, aA2 = 0.f, aA3 = 0.f;
        float aB0 = zxc.y, aB1 = 0.f, aB2 = 0.f, aB3 = 0.f;
#pragma unroll
        for (int q = 0; q < HID / 4; ++q) {
            f4 hv = hb4[q];                       // LDS broadcast, conflict-free
            aA0 = fmaf(hv.x, whA[4 * q + 0], aA0);
            aA1 = fmaf(hv.y, whA[4 * q + 1], aA1);
            aA2 = fmaf(hv.z, whA[4 * q + 2], aA2);
            aA3 = fmaf(hv.w, whA[4 * q + 3], aA3);
            aB0 = fmaf(hv.x, whB[4 * q + 0], aB0);
            aB1 = fmaf(hv.y, whB[4 * q + 1], aB1);
            aB2 = fmaf(hv.z, whB[4 * q + 2], aB2);
            aB3 = fmaf(hv.w, whB[4 * q + 3], aB3);
        }
        float zA = (aA0 + aA1) + (aA2 + aA3);
        float zB = (aB0 + aB1) + (aB2 + aB3);

        // ---- own-gate activations (both waves busy, wave-uniform branch) ----
        float actA, actB;
        if (w == 0) {                  // i, f
            actA = sigmoid_f(zA);
            actB = sigmoid_f(zB);
        } else {                       // g, o
            actA = tanh_f(zA);
            actB = sigmoid_f(zB);
            f2 go; go.x = actA; go.y = actB;
            act2[u] = go;
        }
        __syncthreads();

        // ---- state update: wave 0, lane-parallel ----
        if (w == 0 && tokc != 0) {     // Keras mask_zero: carry when padded
            f2 go = act2[u];
            c = fmaf(actB, c, actA * go.x);        // c = f*c + i*g
            hbuf[u] = go.y * tanh_f(c);            // h = o*tanh(c)
        }
        __syncthreads();

        tokc = tokn; tokn = tokf; zxc = zxn;
    }

    if (w == 0)
        out[row * (2 * HID) + dir * HID + u] = hbuf[u];
}

extern "C" void kernel_launch(void* const* d_in, const int* in_sizes, int n_in,
                              void* d_out, int out_size, void* d_ws, size_t ws_size,
                              hipStream_t stream) {
    const int*   tokens = (const int*)  d_in[0];
    const float* emb    = (const float*)d_in[1];
    const float* Wx_f   = (const float*)d_in[2];
    const float* Wh_f   = (const float*)d_in[3];
    const float* b_f    = (const float*)d_in[4];
    const float* Wx_b   = (const float*)d_in[5];
    const float* Wh_b   = (const float*)d_in[6];
    const float* b_b    = (const float*)d_in[7];
    float* out = (float*)d_out;

    float* zx_tab = (float*)d_ws;   // 2*1000*256*4 = 1.95 MB of d_ws

    hipLaunchKernelGGL(zx_table_kernel, dim3(2 * VOCAB), dim3(GATES), 0, stream,
                       emb, Wx_f, b_f, Wx_b, b_b, zx_tab);
    hipLaunchKernelGGL(lstm_rec_kernel, dim3(2 * B_TOT), dim3(128), 0, stream,
                       tokens, Wh_f, Wh_b, zx_tab, out);
}